// Round 1
// baseline (9941.241 us; speedup 1.0000x reference)
//
#include <hip/hip_runtime.h>
#include <hip/hip_bf16.h>

#define Bsz 128
#define Lseq 512
#define Edim 256
#define Hdim 256
#define Tn 16
#define START_TAG 14
#define END_TAG 15

__device__ __forceinline__ float sigmoidf_(float x) {
    return 1.0f / (1.0f + __expf(-x));
}

// w: [4H, 256] row-major  ->  wt: [256, 4H] (k-major so gate-col loads vectorize)
__global__ void transpose_w_kernel(const float* __restrict__ w, float* __restrict__ wt) {
    int k = blockIdx.x;            // 0..255
    for (int c = threadIdx.x; c < 4 * Hdim; c += blockDim.x)
        wt[k * (4 * Hdim) + c] = w[c * 256 + k];
}

__global__ void lengths_kernel(const int* __restrict__ tag, int* __restrict__ lengths) {
    int b = blockIdx.x;
    int tid = threadIdx.x;
    int cnt = 0;
    for (int l = tid; l < Lseq; l += blockDim.x)
        cnt += (tag[b * Lseq + l] != 0) ? 1 : 0;
    for (int off = 32; off > 0; off >>= 1) cnt += __shfl_down(cnt, off);
    __shared__ int red[4];
    if ((tid & 63) == 0) red[tid >> 6] = cnt;
    __syncthreads();
    if (tid == 0) lengths[b] = red[0] + red[1] + red[2] + red[3];
}

// grid: (16 unit-groups, 8 batch-groups, 2 dirs), block: 256
// Each WG owns 16 hidden units x 16 batches: computes 64 gate columns,
// updates c/h for those units, atomically adds its emission contribution.
// h is parity double-buffered: blocks read h[parity], write h[parity^1],
// so there is no intra-launch read/write race across unit-group blocks.
__global__ __launch_bounds__(256) void lstm_step_kernel(
    const int* __restrict__ bd, const float* __restrict__ emb,
    const float* __restrict__ wiht, const float* __restrict__ whht,   // [2][256*1024] k-major
    const float* __restrict__ bias_f, const float* __restrict__ bias_b,
    const float* __restrict__ w_cls,
    float* __restrict__ hbuf,   // [2 dir][2 parity][B*H]
    float* __restrict__ cbuf,   // [2 dir][B*H]
    float* __restrict__ emission, int step)
{
    const int ug  = blockIdx.x;
    const int bg  = blockIdx.y;
    const int dir = blockIdx.z;
    const int t   = dir ? (Lseq - 1 - step) : step;
    const int tid = threadIdx.x;

    __shared__ float x_lds[16][Edim + 1];
    __shared__ float h_lds[16][Hdim + 1];
    __shared__ float g_lds[16][68];
    __shared__ float hs_lds[16][17];

    const float* hsrc = hbuf + (size_t)(dir * 2 + (step & 1)) * Bsz * Hdim;
    float*       hdst = hbuf + (size_t)(dir * 2 + ((step & 1) ^ 1)) * Bsz * Hdim;

    for (int r = 0; r < 16; ++r) {
        int b = bg * 16 + r;
        int tok = bd[b * Lseq + t];
        x_lds[r][tid] = emb[(size_t)tok * Edim + tid];
        h_lds[r][tid] = hsrc[b * Hdim + tid];
    }
    __syncthreads();

    // gate GEMM: thread (bi, cq) computes 4 consecutive gate cols for one batch row
    const int bi   = tid >> 4;          // 0..15 batch within group
    const int cq   = tid & 15;          // col quad 0..15 -> local cols cq*4..cq*4+3
    const int cl0  = cq * 4;            // 0..63, gate-major: gate = cl0/16
    const int gate = cl0 >> 4;
    const int ul   = cl0 & 15;
    const int gcol = gate * 256 + ug * 16 + ul;   // global gate column (multiple of 4)

    const float* wih  = wiht + (size_t)dir * (Edim * 4 * Hdim);
    const float* whh  = whht + (size_t)dir * (Hdim * 4 * Hdim);
    const float* bias = dir ? bias_b : bias_f;

    float4 acc = *(const float4*)(bias + gcol);
    #pragma unroll 4
    for (int k = 0; k < 256; ++k) {
        float4 wi = *(const float4*)(wih + (size_t)k * 1024 + gcol);
        float4 wh = *(const float4*)(whh + (size_t)k * 1024 + gcol);
        float xv = x_lds[bi][k];
        float hv = h_lds[bi][k];
        acc.x += xv * wi.x + hv * wh.x;
        acc.y += xv * wi.y + hv * wh.y;
        acc.z += xv * wi.z + hv * wh.z;
        acc.w += xv * wi.w + hv * wh.w;
    }
    *(float4*)&g_lds[bi][cl0] = acc;
    __syncthreads();

    // cell update: thread (b, u)
    const int b = tid >> 4;
    const int u = tid & 15;
    float iv = g_lds[b][u];
    float fv = g_lds[b][16 + u];
    float gv = g_lds[b][32 + u];
    float ov = g_lds[b][48 + u];
    int gb = bg * 16 + b;
    int gu = ug * 16 + u;
    int hidx = dir * Bsz * Hdim + gb * Hdim + gu;
    float c_old = cbuf[hidx];
    float cn = sigmoidf_(fv) * c_old + sigmoidf_(iv) * tanhf(gv);
    float hn = sigmoidf_(ov) * tanhf(cn);
    cbuf[hidx] = cn;
    hdst[gb * Hdim + gu] = hn;
    hs_lds[b][u] = hn;
    __syncthreads();

    // emission contribution: thread (b, j=u): sum over this WG's 16 units
    const int j = u;
    const float* wc = w_cls + j * (2 * Hdim) + dir * Hdim + ug * 16;
    float s = 0.f;
    #pragma unroll
    for (int u2 = 0; u2 < 16; ++u2)
        s += hs_lds[b][u2] * wc[u2];
    atomicAdd(&emission[((size_t)gb * Lseq + t) * Tn + j], s);
}

__global__ void golden_kernel(const int* __restrict__ tag,
                              const float* __restrict__ emission,
                              const float* __restrict__ b_cls,
                              const float* __restrict__ trans,
                              float* __restrict__ golden)
{
    int b = blockIdx.x;
    int tid = threadIdx.x;
    float s = 0.f;
    for (int l = tid; l < Lseq; l += blockDim.x) {
        int tg = tag[b * Lseq + l];
        if (tg != 0) {
            int prev = (l == 0) ? START_TAG : tag[b * Lseq + l - 1];
            s += emission[((size_t)b * Lseq + l) * Tn + tg] + b_cls[tg] + trans[prev * Tn + tg];
        }
    }
    for (int off = 32; off > 0; off >>= 1) s += __shfl_down(s, off);
    __shared__ float red[4];
    if ((tid & 63) == 0) red[tid >> 6] = s;
    __syncthreads();
    if (tid == 0) atomicAdd(golden, red[0] + red[1] + red[2] + red[3]);
}

// one block (64 threads) per batch; lanes hold alpha[j], j = lane & 15
__global__ void crf_forward_kernel(const float* __restrict__ emission,
                                   const float* __restrict__ b_cls,
                                   const float* __restrict__ trans,
                                   const int* __restrict__ lengths,
                                   float* __restrict__ allpath)
{
    int b = blockIdx.x;
    int lane = threadIdx.x;
    int j = lane & 15;
    float tcol[16];
    #pragma unroll
    for (int i = 0; i < 16; ++i) tcol[i] = trans[i * Tn + j];
    float bc = b_cls[j];
    float alpha = emission[((size_t)b * Lseq) * Tn + j] + bc + tcol[START_TAG];
    int len = lengths[b];
    for (int t = 1; t < Lseq; ++t) {
        float av[16];
        float m = -1e30f;
        #pragma unroll
        for (int i = 0; i < 16; ++i) {
            av[i] = __shfl(alpha, i) + tcol[i];
            m = fmaxf(m, av[i]);
        }
        float s = 0.f;
        #pragma unroll
        for (int i = 0; i < 16; ++i) s += __expf(av[i] - m);
        float nv = emission[((size_t)b * Lseq + t) * Tn + j] + bc + m + __logf(s);
        alpha = (t < len) ? nv : alpha;
    }
    if (lane == END_TAG) atomicAdd(allpath, alpha);
}

__global__ void finalize_kernel(const float* __restrict__ scal, float* __restrict__ out) {
    out[0] = (scal[1] - scal[0]) / (float)Bsz;
}

extern "C" void kernel_launch(void* const* d_in, const int* in_sizes, int n_in,
                              void* d_out, int out_size, void* d_ws, size_t ws_size,
                              hipStream_t stream)
{
    (void)in_sizes; (void)n_in; (void)out_size; (void)ws_size;
    const int*   bd     = (const int*)d_in[0];
    const int*   tag    = (const int*)d_in[1];
    const float* emb    = (const float*)d_in[2];
    const float* w_ih_f = (const float*)d_in[3];
    const float* w_hh_f = (const float*)d_in[4];
    const float* b_f    = (const float*)d_in[5];
    const float* w_ih_b = (const float*)d_in[6];
    const float* w_hh_b = (const float*)d_in[7];
    const float* b_b    = (const float*)d_in[8];
    const float* w_cls  = (const float*)d_in[9];
    const float* b_cls  = (const float*)d_in[10];
    const float* trans  = (const float*)d_in[11];
    float* out = (float*)d_out;

    float* ws       = (float*)d_ws;
    float* emission = ws;                                   // B*L*T = 1048576
    float* hbuf     = emission + (size_t)Bsz * Lseq * Tn;   // 4 * B*H (dir x parity)
    float* cbuf     = hbuf + 4 * (size_t)Bsz * Hdim;        // 2 * B*H
    float* scal     = cbuf + 2 * (size_t)Bsz * Hdim;        // [0]=golden [1]=allpath, pad 8
    int*   lengths  = (int*)(scal + 8);                     // 128 ints
    float* wiht     = (float*)(lengths + 128);              // 2 * 256*1024
    float* whht     = wiht + 2 * (size_t)Edim * 4 * Hdim;   // 2 * 256*1024

    size_t zero_floats = (size_t)Bsz * Lseq * Tn + 4 * (size_t)Bsz * Hdim
                       + 2 * (size_t)Bsz * Hdim + 8;
    hipMemsetAsync(d_ws, 0, zero_floats * sizeof(float), stream);

    transpose_w_kernel<<<256, 256, 0, stream>>>(w_ih_f, wiht);
    transpose_w_kernel<<<256, 256, 0, stream>>>(w_hh_f, whht);
    transpose_w_kernel<<<256, 256, 0, stream>>>(w_ih_b, wiht + (size_t)Edim * 4 * Hdim);
    transpose_w_kernel<<<256, 256, 0, stream>>>(w_hh_b, whht + (size_t)Hdim * 4 * Hdim);
    lengths_kernel<<<Bsz, 256, 0, stream>>>(tag, lengths);

    for (int step = 0; step < Lseq; ++step) {
        lstm_step_kernel<<<dim3(16, 8, 2), 256, 0, stream>>>(
            bd, emb, wiht, whht, b_f, b_b, w_cls, hbuf, cbuf, emission, step);
    }

    golden_kernel<<<Bsz, 256, 0, stream>>>(tag, emission, b_cls, trans, scal);
    crf_forward_kernel<<<Bsz, 64, 0, stream>>>(emission, b_cls, trans, lengths, scal + 1);
    finalize_kernel<<<1, 1, 0, stream>>>(scal, out);
}